// Round 10
// baseline (785.232 us; speedup 1.0000x reference)
//
#include <hip/hip_runtime.h>
#include <math.h>
#include <stdint.h>

// ============================================================================
// MultiHeadAttention B=4 S=2048 D=1024 H=16 DK=DV=64, fp32 in/out.
// Precision-hardened split-bf16: Q/K path carried as THREE bf16 planes
// (h/m/l, 2^-26) with 6-term MFMA products; V/P/O paths hi/lo 3-term.
// Scores sigma=1024, softmax near-one-hot; near-tie rows amplify score error
// ~1200x into the output. 2-plane path: score err 1.2e-2 -> absmax 32
// (observed r3). This: score err ~3.6e-4 -> predicted absmax ~1.
// The reference's +1e-15 "causal mask" is a numerical no-op in fp32 -> dropped.
// Workspace: EXACTLY 150,994,944 bytes (the r3-proven footprint).
//   - xl plane lives in d_out[0,16MB) (dead before gemm_v writes vth there)
//   - Wo planes alias the wq slots (wsplit_t(Wo) launched after gemm_qk(Q))
// ============================================================================

typedef short bf16x8 __attribute__((ext_vector_type(8)));
typedef float f32x4 __attribute__((ext_vector_type(4)));
typedef unsigned short us8 __attribute__((ext_vector_type(8)));
typedef unsigned short us4 __attribute__((ext_vector_type(4)));

#define MFMA16(acc, a, b) \
    (acc) = __builtin_amdgcn_mfma_f32_16x16x32_bf16((a), (b), (acc), 0, 0, 0)

__device__ __forceinline__ unsigned short f2bf(float x) {   // RNE fp32->bf16
    unsigned int u = __float_as_uint(x);
    unsigned int r = u + 0x7fffu + ((u >> 16) & 1u);
    return (unsigned short)(r >> 16);
}
__device__ __forceinline__ float bf2f(unsigned short h) {
    return __uint_as_float(((unsigned int)h) << 16);
}
__device__ __forceinline__ void gload16(const void* g, void* l) {
    __builtin_amdgcn_global_load_lds(
        (const __attribute__((address_space(1))) void*)g,
        (__attribute__((address_space(3))) void*)l, 16, 0, 0);
}

// ---------------------------------------------------------------------------
// split x -> 3 bf16 planes (h/m/l): x = h + m + l + O(2^-26 x)
// ---------------------------------------------------------------------------
__global__ __launch_bounds__(256)
void splitx3(const float* __restrict__ x, unsigned short* __restrict__ xh,
             unsigned short* __restrict__ xm, unsigned short* __restrict__ xl) {
    const size_t i = ((size_t)blockIdx.x * 256 + threadIdx.x) * 8;
    float4 a = *(const float4*)(x + i);
    float4 b = *(const float4*)(x + i + 4);
    float v[8] = {a.x, a.y, a.z, a.w, b.x, b.y, b.z, b.w};
    us8 h, m, l;
    #pragma unroll
    for (int j = 0; j < 8; ++j) {
        unsigned short hh = f2bf(v[j]);
        float r1 = v[j] - bf2f(hh);
        unsigned short mm = f2bf(r1);
        h[j] = hh; m[j] = mm; l[j] = f2bf(r1 - bf2f(mm));
    }
    *(us8*)(xh + i) = h;
    *(us8*)(xm + i) = m;
    *(us8*)(xl + i) = l;
}

// ---------------------------------------------------------------------------
// transpose+split weights -> [N_glob][1024] bf16 planes, 3-plane variant.
// qkv use: ldin=64, sliceStride=65536, rowsPerSlice=64, grid(1,16,16)
// ---------------------------------------------------------------------------
__global__ __launch_bounds__(256)
void wsplit_t3(const float* __restrict__ in, unsigned short* __restrict__ oH,
               unsigned short* __restrict__ oM, unsigned short* __restrict__ oL,
               int ldin, size_t sliceStride, int rowsPerSlice) {
    __shared__ __align__(16) float Tf[64][68];
    const int t = threadIdx.x;
    const int n0 = blockIdx.x * 64, k0 = blockIdx.y * 64, sl = blockIdx.z;
    const float* ip = in + (size_t)sl * sliceStride;
    {
        const int kr = t >> 2, c4 = (t & 3) * 16;
        #pragma unroll
        for (int j = 0; j < 4; ++j)
            *(float4*)&Tf[kr][c4 + j * 4] =
                *(const float4*)(ip + (size_t)(k0 + kr) * ldin + n0 + c4 + j * 4);
    }
    __syncthreads();
    {
        const int c = t >> 2, kc = (t & 3) * 16;
        us8 hv[2], mv[2], lv[2];
        #pragma unroll
        for (int g = 0; g < 2; ++g)
            #pragma unroll
            for (int i = 0; i < 8; ++i) {
                float v = Tf[kc + g * 8 + i][c];
                unsigned short hh = f2bf(v);
                float r1 = v - bf2f(hh);
                unsigned short mm = f2bf(r1);
                hv[g][i] = hh; mv[g][i] = mm; lv[g][i] = f2bf(r1 - bf2f(mm));
            }
        const size_t ob = (size_t)(sl * rowsPerSlice + n0 + c) * 1024 + k0 + kc;
        *(us8*)(oH + ob) = hv[0]; *(us8*)(oH + ob + 8) = hv[1];
        *(us8*)(oM + ob) = mv[0]; *(us8*)(oM + ob + 8) = mv[1];
        *(us8*)(oL + ob) = lv[0]; *(us8*)(oL + ob + 8) = lv[1];
    }
}

// 2-plane variant (Wv, Wo)
__global__ __launch_bounds__(256)
void wsplit_t(const float* __restrict__ in, unsigned short* __restrict__ oH,
              unsigned short* __restrict__ oL, int ldin, size_t sliceStride,
              int rowsPerSlice) {
    __shared__ __align__(16) float Tf[64][68];
    const int t = threadIdx.x;
    const int n0 = blockIdx.x * 64, k0 = blockIdx.y * 64, sl = blockIdx.z;
    const float* ip = in + (size_t)sl * sliceStride;
    {
        const int kr = t >> 2, c4 = (t & 3) * 16;
        #pragma unroll
        for (int j = 0; j < 4; ++j)
            *(float4*)&Tf[kr][c4 + j * 4] =
                *(const float4*)(ip + (size_t)(k0 + kr) * ldin + n0 + c4 + j * 4);
    }
    __syncthreads();
    {
        const int c = t >> 2, kc = (t & 3) * 16;
        us8 hv[2], lv[2];
        #pragma unroll
        for (int g = 0; g < 2; ++g)
            #pragma unroll
            for (int i = 0; i < 8; ++i) {
                float v = Tf[kc + g * 8 + i][c];
                unsigned short hh = f2bf(v);
                hv[g][i] = hh; lv[g][i] = f2bf(v - bf2f(hh));
            }
        const size_t ob = (size_t)(sl * rowsPerSlice + n0 + c) * 1024 + k0 + kc;
        *(us8*)(oH + ob) = hv[0]; *(us8*)(oH + ob + 8) = hv[1];
        *(us8*)(oL + ob) = lv[0]; *(us8*)(oL + ob + 8) = lv[1];
    }
}

// ---------------------------------------------------------------------------
// K1a: Q or K projection, 6-term split-bf16 (error ~fp32 level).
// [8192 x 1024] x [1024 x 64-per-head]. 64x64 tile, 4 waves (2x2 of 32x32),
// BK=64. LDS 48KB: A h/m/l + B h/m/l, 8KB each, XOR-swizzled.
// Output: 3 bf16 planes in [b*16+h][s][64] layout; Q pre-scaled 1/sqrt(64).
// ---------------------------------------------------------------------------
__global__ __launch_bounds__(256)
void gemm_qk(const unsigned short* __restrict__ xh, const unsigned short* __restrict__ xm,
             const unsigned short* __restrict__ xl,
             const unsigned short* __restrict__ wh, const unsigned short* __restrict__ wm,
             const unsigned short* __restrict__ wl,
             unsigned short* __restrict__ OH, unsigned short* __restrict__ OM,
             unsigned short* __restrict__ OL, float mult) {
    __shared__ __align__(16) char sm[49152];
    const int t = threadIdx.x, lane = t & 63;
    const int w = t >> 6, wm_ = w >> 1, wn_ = w & 1;
    const int m0 = blockIdx.y * 64;
    const int head = blockIdx.x;          // n-tile == one head (64 cols)
    const int nb = head * 64;

    const f32x4 zz = {0.f, 0.f, 0.f, 0.f};
    f32x4 acc[2][2];
    #pragma unroll
    for (int i = 0; i < 2; ++i)
        #pragma unroll
        for (int j = 0; j < 2; ++j) acc[i][j] = zz;

    for (int kt = 0; kt < 1024; kt += 64) {
        __syncthreads();
        #pragma unroll
        for (int p = 0; p < 2; ++p) {
            const int ldsb = p * 4096 + t * 16;
            const int row = ldsb >> 7;
            const int cp = (t & 7) ^ (row & 7);
            gload16(xh + (size_t)(m0 + row) * 1024 + kt + cp * 8, sm + ldsb);
            gload16(xm + (size_t)(m0 + row) * 1024 + kt + cp * 8, sm + 8192 + ldsb);
            gload16(xl + (size_t)(m0 + row) * 1024 + kt + cp * 8, sm + 16384 + ldsb);
            gload16(wh + (size_t)(nb + row) * 1024 + kt + cp * 8, sm + 24576 + ldsb);
            gload16(wm + (size_t)(nb + row) * 1024 + kt + cp * 8, sm + 32768 + ldsb);
            gload16(wl + (size_t)(nb + row) * 1024 + kt + cp * 8, sm + 40960 + ldsb);
        }
        __syncthreads();
        #pragma unroll
        for (int ks = 0; ks < 2; ++ks) {
            bf16x8 fah[2], fam[2], fal[2], fbh[2], fbm[2], fbl[2];
            #pragma unroll
            for (int f = 0; f < 2; ++f) {
                const int rA = wm_ * 32 + f * 16 + (lane & 15);
                const int oA = ((rA * 128) + ks * 64 + (lane >> 4) * 16) ^ ((lane & 7) << 4);
                fah[f] = *(const bf16x8*)(sm + oA);
                fam[f] = *(const bf16x8*)(sm + 8192 + oA);
                fal[f] = *(const bf16x8*)(sm + 16384 + oA);
                const int rB = wn_ * 32 + f * 16 + (lane & 15);
                const int oB = ((rB * 128) + ks * 64 + (lane >> 4) * 16) ^ ((lane & 7) << 4);
                fbh[f] = *(const bf16x8*)(sm + 24576 + oB);
                fbm[f] = *(const bf16x8*)(sm + 32768 + oB);
                fbl[f] = *(const bf16x8*)(sm + 40960 + oB);
            }
            #pragma unroll
            for (int fm = 0; fm < 2; ++fm)
                #pragma unroll
                for (int fn = 0; fn < 2; ++fn) {
                    MFMA16(acc[fm][fn], fah[fm], fbh[fn]);   // hh
                    MFMA16(acc[fm][fn], fah[fm], fbm[fn]);   // hm
                    MFMA16(acc[fm][fn], fam[fm], fbh[fn]);   // mh
                    MFMA16(acc[fm][fn], fah[fm], fbl[fn]);   // hl
                    MFMA16(acc[fm][fn], fal[fm], fbh[fn]);   // lh
                    MFMA16(acc[fm][fn], fam[fm], fbm[fn]);   // mm
                }
        }
    }
    #pragma unroll
    for (int fm = 0; fm < 2; ++fm)
        #pragma unroll
        for (int fn = 0; fn < 2; ++fn)
            #pragma unroll
            for (int r = 0; r < 4; ++r) {
                const int mg = m0 + wm_ * 32 + fm * 16 + (lane >> 4) * 4 + r;
                const int c = wn_ * 32 + fn * 16 + (lane & 15);
                const int b = mg >> 11, s = mg & 2047;
                const size_t o = ((size_t)(b * 16 + head) * 2048 + s) * 64 + c;
                const float v = acc[fm][fn][r] * mult;
                const unsigned short hh = f2bf(v);
                const float r1 = v - bf2f(hh);
                const unsigned short mm = f2bf(r1);
                OH[o] = hh; OM[o] = mm; OL[o] = f2bf(r1 - bf2f(mm));
            }
}

// ---------------------------------------------------------------------------
// K1b: V projection, 3-term split-bf16 (x represented by h+m planes).
// 128x128 tile, writes V^T hi/lo planes DIRECTLY: [b*16+h][dv][s].
// ---------------------------------------------------------------------------
__global__ __launch_bounds__(256)
void gemm_v(const unsigned short* __restrict__ xh, const unsigned short* __restrict__ xm,
            const unsigned short* __restrict__ wh, const unsigned short* __restrict__ wl,
            unsigned short* __restrict__ Vth, unsigned short* __restrict__ Vtl) {
    __shared__ __align__(16) char sm[65536];
    char* Ah = sm;
    char* Al = sm + 16384;
    char* Bh = sm + 32768;
    char* Bl = sm + 49152;
    const int t = threadIdx.x, lane = t & 63;
    const int w = t >> 6, wm_ = w >> 1, wn_ = w & 1;
    const int m0 = blockIdx.y * 128;
    const int nb = blockIdx.x * 128;

    const f32x4 zz = {0.f, 0.f, 0.f, 0.f};
    f32x4 acc[4][4];
    #pragma unroll
    for (int i = 0; i < 4; ++i)
        #pragma unroll
        for (int j = 0; j < 4; ++j) acc[i][j] = zz;

    for (int kt = 0; kt < 1024; kt += 64) {
        __syncthreads();
        #pragma unroll
        for (int p = 0; p < 4; ++p) {
            const int ldsb = p * 4096 + t * 16;
            const int row = ldsb >> 7;
            const int cp = (t & 7) ^ (row & 7);
            gload16(xh + (size_t)(m0 + row) * 1024 + kt + cp * 8, Ah + ldsb);
            gload16(xm + (size_t)(m0 + row) * 1024 + kt + cp * 8, Al + ldsb);
            gload16(wh + (size_t)(nb + row) * 1024 + kt + cp * 8, Bh + ldsb);
            gload16(wl + (size_t)(nb + row) * 1024 + kt + cp * 8, Bl + ldsb);
        }
        __syncthreads();
        #pragma unroll
        for (int ks = 0; ks < 2; ++ks) {
            bf16x8 fah[4], fal[4], fbh[4], fbl[4];
            #pragma unroll
            for (int f = 0; f < 4; ++f) {
                const int rA = wm_ * 64 + f * 16 + (lane & 15);
                const int oA = ((rA * 128) + ks * 64 + (lane >> 4) * 16) ^ ((lane & 7) << 4);
                fah[f] = *(const bf16x8*)(Ah + oA);
                fal[f] = *(const bf16x8*)(Al + oA);
                const int rB = wn_ * 64 + f * 16 + (lane & 15);
                const int oB = ((rB * 128) + ks * 64 + (lane >> 4) * 16) ^ ((lane & 7) << 4);
                fbh[f] = *(const bf16x8*)(Bh + oB);
                fbl[f] = *(const bf16x8*)(Bl + oB);
            }
            #pragma unroll
            for (int fm = 0; fm < 4; ++fm)
                #pragma unroll
                for (int fn = 0; fn < 4; ++fn) {
                    MFMA16(acc[fm][fn], fah[fm], fbh[fn]);
                    MFMA16(acc[fm][fn], fah[fm], fbl[fn]);
                    MFMA16(acc[fm][fn], fal[fm], fbh[fn]);
                }
        }
    }
    // transposed epilogue: V^T[bh][dv][s], 4 consecutive s per store (8B)
    #pragma unroll
    for (int fm = 0; fm < 4; ++fm)
        #pragma unroll
        for (int fn = 0; fn < 4; ++fn) {
            const int mg = m0 + wm_ * 64 + fm * 16 + (lane >> 4) * 4;
            const int n = nb + wn_ * 64 + fn * 16 + (lane & 15);
            const int b = mg >> 11, s0 = mg & 2047;
            const int head = n >> 6, dv = n & 63;
            us4 hv, lv;
            #pragma unroll
            for (int r = 0; r < 4; ++r) {
                const float v = acc[fm][fn][r];
                hv[r] = f2bf(v);
                lv[r] = f2bf(v - bf2f(hv[r]));
            }
            const size_t o = (size_t)(b * 16 + head) * 131072 + (size_t)dv * 2048 + s0;
            *(us4*)(Vth + o) = hv;
            *(us4*)(Vtl + o) = lv;
        }
}

// ---------------------------------------------------------------------------
// K2: flash attention. 6-term QK^T (Q,K 3-plane), 3-term PV (P,V hi/lo).
// Block = (bh, 64-query tile), 4 waves x 16 q-rows. KV tiles of 64.
// LDS 56KB: K h/m/l 24KB @0 | V h/l 16KB @24576 (single buffer) |
//           P h/l 16KB @40960. Q staged through K region in prologue.
// V(kv+1) prefetched global->REGISTERS during QK/softmax, ds_written after
// PV's barrier (T14 async-STAGE split). 3 barriers per kv tile.
// ---------------------------------------------------------------------------
__global__ __launch_bounds__(256)
void attn(const unsigned short* __restrict__ Qh, const unsigned short* __restrict__ Qm,
          const unsigned short* __restrict__ Ql,
          const unsigned short* __restrict__ Kh, const unsigned short* __restrict__ Km,
          const unsigned short* __restrict__ Kl,
          const unsigned short* __restrict__ Vth, const unsigned short* __restrict__ Vtl,
          unsigned short* __restrict__ OhP, unsigned short* __restrict__ OlP) {
    __shared__ __align__(16) char sm[57344];
    const int t = threadIdx.x, lane = t & 63, w = t >> 6;
    const int bh = blockIdx.y;
    const int q0 = blockIdx.x * 64;
    const size_t pbase = (size_t)bh * 2048 * 64;
    const unsigned short* Qhp = Qh + pbase + (size_t)q0 * 64;
    const unsigned short* Qmp = Qm + pbase + (size_t)q0 * 64;
    const unsigned short* Qlp = Ql + pbase + (size_t)q0 * 64;
    const unsigned short* Khp = Kh + pbase;
    const unsigned short* Kmp = Km + pbase;
    const unsigned short* Klp = Kl + pbase;
    const unsigned short* Vhp = Vth + (size_t)bh * 131072;
    const unsigned short* Vlp = Vtl + (size_t)bh * 131072;

    // prologue 1: stage Q (3 planes) into the K region
    #pragma unroll
    for (int p = 0; p < 2; ++p) {
        const int ldsb = p * 4096 + t * 16;
        const int row = ldsb >> 7;
        const int cp = (t & 7) ^ (row & 7);
        gload16(Qhp + (size_t)row * 64 + cp * 8, sm + ldsb);
        gload16(Qmp + (size_t)row * 64 + cp * 8, sm + 8192 + ldsb);
        gload16(Qlp + (size_t)row * 64 + cp * 8, sm + 16384 + ldsb);
    }
    __syncthreads();
    bf16x8 fqh[2], fqm[2], fql[2];
    #pragma unroll
    for (int ks = 0; ks < 2; ++ks) {
        const int rQ = w * 16 + (lane & 15);
        const int oQ = ((rQ * 128) + ks * 64 + (lane >> 4) * 16) ^ ((lane & 7) << 4);
        fqh[ks] = *(const bf16x8*)(sm + oQ);
        fqm[ks] = *(const bf16x8*)(sm + 8192 + oQ);
        fql[ks] = *(const bf16x8*)(sm + 16384 + oQ);
    }
    __syncthreads();                          // Q in regs before K overwrites

    // prologue 2: stage K(0) (3 planes) and V(0) (2 planes)
    #pragma unroll
    for (int p = 0; p < 2; ++p) {
        const int ldsb = p * 4096 + t * 16;
        const int row = ldsb >> 7;
        const int cp = (t & 7) ^ (row & 7);
        gload16(Khp + (size_t)row * 64 + cp * 8, sm + ldsb);
        gload16(Kmp + (size_t)row * 64 + cp * 8, sm + 8192 + ldsb);
        gload16(Klp + (size_t)row * 64 + cp * 8, sm + 16384 + ldsb);
        gload16(Vhp + (size_t)row * 2048 + cp * 8, sm + 24576 + ldsb);
        gload16(Vlp + (size_t)row * 2048 + cp * 8, sm + 32768 + ldsb);
    }

    // V register-prefetch thread mapping
    const int vpl = t >> 7;                   // 0: hi plane, 1: lo plane
    const int vu = t & 127;
    const int vdv = vu >> 1;
    const int vhf = vu & 1;
    const unsigned short* vsrc_base =
        (vpl ? Vlp : Vhp) + (size_t)vdv * 2048 + vhf * 32;
    const int vldsbase = 24576 + vpl * 8192 + vdv * 128;

    const f32x4 zz = {0.f, 0.f, 0.f, 0.f};
    f32x4 o4[4];
    float m_run[4], l_run[4];
    #pragma unroll
    for (int i = 0; i < 4; ++i) { o4[i] = zz; m_run[i] = -1e30f; l_run[i] = 0.f; }

    for (int kv = 0; kv < 32; ++kv) {
        __syncthreads();                      // B3: K(kv),V(kv) ready in LDS

        // --- QK^T, 6-term ---
        f32x4 s4[4] = {zz, zz, zz, zz};
        #pragma unroll
        for (int ks = 0; ks < 2; ++ks)
            #pragma unroll
            for (int fn = 0; fn < 4; ++fn) {
                const int rK = fn * 16 + (lane & 15);
                const int oK = ((rK * 128) + ks * 64 + (lane >> 4) * 16) ^ ((lane & 7) << 4);
                const bf16x8 kh8 = *(const bf16x8*)(sm + oK);
                const bf16x8 km8 = *(const bf16x8*)(sm + 8192 + oK);
                const bf16x8 kl8 = *(const bf16x8*)(sm + 16384 + oK);
                MFMA16(s4[fn], fqh[ks], kh8);
                MFMA16(s4[fn], fqh[ks], km8);
                MFMA16(s4[fn], fqm[ks], kh8);
                MFMA16(s4[fn], fqh[ks], kl8);
                MFMA16(s4[fn], fql[ks], kh8);
                MFMA16(s4[fn], fqm[ks], km8);
            }

        // --- issue V(kv+1) global->reg prefetch (hidden under softmax+PV) ---
        us8 vr0, vr1, vr2, vr3;
        if (kv < 31) {
            const unsigned short* vs = vsrc_base + (kv + 1) * 64;
            vr0 = *(const us8*)(vs);
            vr1 = *(const us8*)(vs + 8);
            vr2 = *(const us8*)(vs + 16);
            vr3 = *(const us8*)(vs + 24);
        }

        // --- online softmax (row = (lane>>4)*4+r, replicated over lane&15) ---
        float pr[4][4];
        #pragma unroll
        for (int r = 0; r < 4; ++r) {
            float mx = fmaxf(fmaxf(s4[0][r], s4[1][r]), fmaxf(s4[2][r], s4[3][r]));
            #pragma unroll
            for (int off = 1; off < 16; off <<= 1) mx = fmaxf(mx, __shfl_xor(mx, off));
            const float mn = fmaxf(m_run[r], mx);
            const float f = __expf(m_run[r] - mn);
            m_run[r] = mn;
            float rs = 0.f;
            #pragma unroll
            for (int fn = 0; fn < 4; ++fn) { pr[fn][r] = __expf(s4[fn][r] - mn); rs += pr[fn][r]; }
            #pragma unroll
            for (int off = 1; off < 16; off <<= 1) rs += __shfl_xor(rs, off);
            l_run[r] = l_run[r] * f + rs;
            #pragma unroll
            for (int fn = 0; fn < 4; ++fn) o4[fn][r] *= f;
        }
        // publish P hi/lo (bf16, swizzled)
        #pragma unroll
        for (int fn = 0; fn < 4; ++fn)
            #pragma unroll
            for (int r = 0; r < 4; ++r) {
                const int row = w * 16 + (lane >> 4) * 4 + r;
                const int key = fn * 16 + (lane & 15);
                const int ob = ((row * 128) + key * 2) ^ ((row & 7) << 4);
                const float p = pr[fn][r];
                const unsigned short ph = f2bf(p);
                *(unsigned short*)(sm + 40960 + ob) = ph;
                *(unsigned short*)(sm + 49152 + ob) = f2bf(p - bf2f(ph));
            }
        __syncthreads();                      // B2: P visible; K region free

        if (kv < 31) {                        // stage K(kv+1), overlaps PV
            const int k0n = (kv + 1) * 64;
            #pragma unroll
            for (int p = 0; p < 2; ++p) {
                const int ldsb = p * 4096 + t * 16;
                const int row = ldsb >> 7;
                const int cp = (t & 7) ^ (row & 7);
                gload16(Khp + (size_t)(k0n + row) * 64 + cp * 8, sm + ldsb);
                gload16(Kmp + (size_t)(k0n + row) * 64 + cp * 8, sm + 8192 + ldsb);
                gload16(Klp + (size_t)(k0n + row) * 64 + cp * 8, sm + 16384 + ldsb);
            }
        }

        // --- PV, 3-term ---
        #pragma unroll
        for (int ks = 0; ks < 2; ++ks) {
            const int rP = w * 16 + (lane & 15);
            const int oP = ((rP * 128) + ks * 64 + (lane >> 4) * 16) ^ ((lane & 7) << 4);
            const bf16x8 fph = *(const bf16x8*)(sm + 40960 + oP);
            const bf16x8 fpl = *(const bf16x8*)(sm + 49152 + oP);
            #pragma unroll
            for (int fn = 0; fn < 4; ++fn) {
                const int rV = fn * 16 + (lane & 15);
                const int oV = ((rV * 128) + ks * 64 + (lane >> 4) * 16) ^ ((lane & 7) << 4);
                const bf16x8 vh8 = *(const bf16x8*)(sm + 24576 + oV);
                const bf16x8 vl8 = *(const bf16x8*)(sm + 32768 + oV);
                MFMA16(o4[fn], fph, vh8);
                MFMA16(o4[fn], fpl, vh8);
                MFMA16(o4[fn], fph, vl8);
            }
        }
        __syncthreads();                      // B2b: PV done -> V region free

        if (kv < 31) {                        // write prefetched V(kv+1)
            *(us8*)(sm + vldsbase + (((vhf * 64) + 0)  ^ ((vdv & 7) << 4))) = vr0;
            *(us8*)(sm + vldsbase + (((vhf * 64) + 16) ^ ((vdv & 7) << 4))) = vr1;
            *(us8*)(sm + vldsbase + (((vhf * 64) + 32) ^ ((vdv & 7) << 4))) = vr2;
            *(us8*)(sm + vldsbase + (((vhf * 64) + 48) ^ ((vdv & 7) << 4))) = vr3;
        }
    }
    // epilogue: O/l, split hi/lo, concat layout [b][s][h*64+dv]
    const int b = bh >> 4, h = bh & 15;
    #pragma unroll
    for (int r = 0; r < 4; ++r) {
        const float inv = 1.f / l_run[r];
        const int q = q0 + w * 16 + (lane >> 4) * 4 + r;
        #pragma unroll
        for (int fn = 0; fn < 4; ++fn) {
            const float v = o4[fn][r] * inv;
            const size_t oo = ((size_t)b * 2048 + q) * 1024 + h * 64 + fn * 16 + (lane & 15);
            const unsigned short hi = f2bf(v);
            OhP[oo] = hi;
            OlP[oo] = f2bf(v - bf2f(hi));
        }
    }
}

// ---------------------------------------------------------------------------
// K3: output projection [8192 x 1024] x [1024 x 1024] -> fp32 d_out. 3-term.
// ---------------------------------------------------------------------------
__global__ __launch_bounds__(256)
void gemm_out(const unsigned short* __restrict__ Oh, const unsigned short* __restrict__ Ol,
              const unsigned short* __restrict__ Wth, const unsigned short* __restrict__ Wtl,
              float* __restrict__ out) {
    __shared__ __align__(16) char sm[65536];
    char* Ah = sm;
    char* Al = sm + 16384;
    char* Bh = sm + 32768;
    char* Bl = sm + 49152;
    const int t = threadIdx.x, lane = t & 63;
    const int w = t >> 6, wm_ = w >> 1, wn_ = w & 1;
    const int m0 = blockIdx.y * 128;
    const int n0 = blockIdx.x * 128;

    const f32x4 zz = {0.f, 0.f, 0.f, 0.f};
    f32x4 acc[4][4];
    #pragma unroll
    for (int i = 0; i < 4; ++i)
        #pragma unroll
        for (int j = 0; j < 4; ++j) acc[i][j] = zz;

    for (int kt = 0; kt < 1024; kt += 64) {
        __syncthreads();
        #pragma unroll
        for (int p = 0; p < 4; ++p) {
            const int ldsb = p * 4096 + t * 16;
            const int row = ldsb >> 7;
            const int cp = (t & 7) ^ (row & 7);
            gload16(Oh + (size_t)(m0 + row) * 1024 + kt + cp * 8, Ah + ldsb);
            gload16(Ol + (size_t)(m0 + row) * 1024 + kt + cp * 8, Al + ldsb);
            gload16(Wth + (size_t)(n0 + row) * 1024 + kt + cp * 8, Bh + ldsb);
            gload16(Wtl + (size_t)(n0 + row) * 1024 + kt + cp * 8, Bl + ldsb);
        }
        __syncthreads();
        #pragma unroll
        for (int ks = 0; ks < 2; ++ks) {
            bf16x8 fah[4], fal[4], fbh[4], fbl[4];
            #pragma unroll
            for (int f = 0; f < 4; ++f) {
                const int rA = wm_ * 64 + f * 16 + (lane & 15);
                const int oA = ((rA * 128) + ks * 64 + (lane >> 4) * 16) ^ ((lane & 7) << 4);
                fah[f] = *(const bf16x8*)(Ah + oA);
                fal[f] = *(const bf16x8*)(Al + oA);
                const int rB = wn_ * 64 + f * 16 + (lane & 15);
                const int oB = ((rB * 128) + ks * 64 + (lane >> 4) * 16) ^ ((lane & 7) << 4);
                fbh[f] = *(const bf16x8*)(Bh + oB);
                fbl[f] = *(const bf16x8*)(Bl + oB);
            }
            #pragma unroll
            for (int fm = 0; fm < 4; ++fm)
                #pragma unroll
                for (int fn = 0; fn < 4; ++fn) {
                    MFMA16(acc[fm][fn], fah[fm], fbh[fn]);
                    MFMA16(acc[fm][fn], fah[fm], fbl[fn]);
                    MFMA16(acc[fm][fn], fal[fm], fbh[fn]);
                }
        }
    }
    #pragma unroll
    for (int fm = 0; fm < 4; ++fm)
        #pragma unroll
        for (int fn = 0; fn < 4; ++fn)
            #pragma unroll
            for (int r = 0; r < 4; ++r) {
                const int m = m0 + wm_ * 64 + fm * 16 + (lane >> 4) * 4 + r;
                const int n = n0 + wn_ * 64 + fn * 16 + (lane & 15);
                out[(size_t)m * 1024 + n] = acc[fm][fn][r];
            }
}

// ---------------------------------------------------------------------------
extern "C" void kernel_launch(void* const* d_in, const int* in_sizes, int n_in,
                              void* d_out, int out_size, void* d_ws, size_t ws_size,
                              hipStream_t stream) {
    (void)in_sizes; (void)n_in; (void)out_size; (void)ws_size;
    const float* x  = (const float*)d_in[0];
    const float* Wq = (const float*)d_in[1];
    const float* Wk = (const float*)d_in[2];
    const float* Wv = (const float*)d_in[3];
    const float* Wo = (const float*)d_in[4];

    // ws layout (bytes). Total: 8*PL + 8*WL = 150,994,944 — EXACTLY the
    // footprint the r3 bench ran with (proven available).
    char* p = (char*)d_ws;
    const size_t PL = 16777216;   // 16MB token-plane
    const size_t WL = 2097152;    // 2MB weight-plane
    unsigned short* xh  = (unsigned short*)(p);            // also Oh after attn
    unsigned short* xm  = (unsigned short*)(p + PL);       // also Ol after attn
    char* wp = p + 2 * PL;
    unsigned short* wqh = (unsigned short*)(wp);           // dead after gemm_qk(Q)
    unsigned short* wqm = (unsigned short*)(wp + WL);      //   -> reused for Wo
    unsigned short* wql = (unsigned short*)(wp + 2 * WL);
    unsigned short* wkh = (unsigned short*)(wp + 3 * WL);
    unsigned short* wkm = (unsigned short*)(wp + 4 * WL);
    unsigned short* wkl = (unsigned short*)(wp + 5 * WL);
    unsigned short* wvh = (unsigned short*)(wp + 6 * WL);
    unsigned short* wvl = (unsigned short*)(wp + 7 * WL);
    char* qp = wp + 8 * WL;
    unsigned short* qh  = (unsigned short*)(qp);
    unsigned short* qm  = (unsigned short*)(qp + PL);
    unsigned short* qlo = (unsigned short*)(qp + 2 * PL);
    unsigned short* kh  = (unsigned short*)(qp + 3 * PL);
    unsigned short* km  = (unsigned short*)(qp + 4 * PL);
    unsigned short* klo = (unsigned short*)(qp + 5 * PL);

    // Aliases with disjoint lifetimes (stream-ordered):
    // - xl lives in d_out[0, PL): written by splitx3, last read by
    //   gemm_qk(K); gemm_v then overwrites that range with vth.
    // - Wo planes live in the wq slots: wsplit_t(Wo) launches AFTER
    //   gemm_qk(Q) (wq's last reader); gemm_out reads them at the end.
    unsigned short* xl  = (unsigned short*)d_out;
    unsigned short* woh = wqh;
    unsigned short* wol = wqm;
    unsigned short* vth = (unsigned short*)d_out;          // overwrites dead xl
    unsigned short* vtl = vth + (size_t)64 * 64 * 2048;

    splitx3<<<4096, 256, 0, stream>>>(x, xh, xm, xl);
    wsplit_t3<<<dim3(1, 16, 16), 256, 0, stream>>>(Wq, wqh, wqm, wql, 64, 65536, 64);
    wsplit_t3<<<dim3(1, 16, 16), 256, 0, stream>>>(Wk, wkh, wkm, wkl, 64, 65536, 64);
    wsplit_t<<<dim3(1, 16, 16), 256, 0, stream>>>(Wv, wvh, wvl, 64, 65536, 64);
    gemm_qk<<<dim3(16, 128), 256, 0, stream>>>(xh, xm, xl, wqh, wqm, wql,
                                               qh, qm, qlo, 0.125f);
    // wq planes now dead -> stage Wo into their slots
    wsplit_t<<<dim3(16, 16, 1), 256, 0, stream>>>(Wo, woh, wol, 1024, 0, 0);
    gemm_qk<<<dim3(16, 128), 256, 0, stream>>>(xh, xm, xl, wkh, wkm, wkl,
                                               kh, km, klo, 1.0f);
    gemm_v<<<dim3(8, 64), 256, 0, stream>>>(xh, xm, wvh, wvl, vth, vtl);
    attn<<<dim3(32, 64), 256, 0, stream>>>(qh, qm, qlo, kh, km, klo,
                                           vth, vtl, xh, xm);
    gemm_out<<<dim3(8, 64), 256, 0, stream>>>(xh, xm, woh, wol, (float*)d_out);
}